// Round 19
// baseline (189.675 us; speedup 1.0000x reference)
//
#include <hip/hip_runtime.h>
#include <hip/hip_bf16.h>
#include <stdint.h>

#define S_LEN 2688
#define DIM   1536
#define NH    12
#define HD    128
#define QKV_N 4608   // 3*DIM

typedef __attribute__((ext_vector_type(8)))  short bf16x8;
typedef __attribute__((ext_vector_type(4)))  float f32x4;
typedef __attribute__((ext_vector_type(16))) float f32x16;

__device__ inline ushort f2bf(float f) {
    uint32_t u = __float_as_uint(f);
    uint32_t r = (u + 0x7fffu + ((u >> 16) & 1u)) >> 16;
    return (ushort)r;
}
__device__ inline float bf2f(uint u) { return __uint_as_float(u << 16); }
__device__ inline float fexp2(float x) {           // raw v_exp_f32 (2^x); args
    float r;                                       // bounded by defer-max
    asm("v_exp_f32 %0, %1" : "=v"(r) : "v"(x));
    return r;
}
__device__ inline uint cvtpk(float lo, float hi) { // 2xf32 -> packed bf16
    uint r;
    asm("v_cvt_pk_bf16_f32 %0, %1, %2" : "=v"(r) : "v"(lo), "v"(hi));
    return r;
}

#define GLOAD16(gp, lp) __builtin_amdgcn_global_load_lds( \
    (__attribute__((address_space(1))) const void*)(gp),  \
    (__attribute__((address_space(3))) void*)(lp), 16, 0, 0)

// ---------------------------------------------------------------------------
// 1) fp32 -> bf16 convert: x and the four weight matrices (fused into wb)
// ---------------------------------------------------------------------------
__global__ __launch_bounds__(256) void convert_all(
    const float* __restrict__ x,
    const float* __restrict__ wq, const float* __restrict__ wk,
    const float* __restrict__ wv, const float* __restrict__ wo,
    ushort* __restrict__ xb, ushort* __restrict__ wb)
{
    const size_t NX4 = (size_t)S_LEN * DIM / 4;   // 1,032,192
    const size_t NW4 = (size_t)DIM * DIM / 4;     //   589,824
    size_t i = (size_t)blockIdx.x * 256 + threadIdx.x;
    const float* src; ushort* dst;
    if (i < NX4)            { src = x;  dst = xb; }
    else if (i < NX4+1*NW4) { src = wq; dst = wb;                        i -= NX4; }
    else if (i < NX4+2*NW4) { src = wk; dst = wb + 1*(size_t)DIM*DIM;    i -= NX4+1*NW4; }
    else if (i < NX4+3*NW4) { src = wv; dst = wb + 2*(size_t)DIM*DIM;    i -= NX4+2*NW4; }
    else if (i < NX4+4*NW4) { src = wo; dst = wb + 3*(size_t)DIM*DIM;    i -= NX4+3*NW4; }
    else return;
    float4 v = reinterpret_cast<const float4*>(src)[i];
    ushort4 o = { f2bf(v.x), f2bf(v.y), f2bf(v.z), f2bf(v.w) };
    reinterpret_cast<ushort4*>(dst)[i] = o;
}

// ---------------------------------------------------------------------------
// 2) QKV GEMM (R15-verified): bf16 out, q/k -> qkb [S][3072];
//    V -> v_t [d][S] transposed. Dbuf staging + both-sides XOR chunk swizzle
//    + XCD remap. A/B history: swizzle ~ -12 µs, dbuf ~ -4.4 µs (R15/R16).
// ---------------------------------------------------------------------------
__global__ __launch_bounds__(256) void gemm_qkv(
    const ushort* __restrict__ A, const ushort* __restrict__ B,
    const float* __restrict__ bq, const float* __restrict__ bk,
    const float* __restrict__ bv,
    ushort* __restrict__ qkb, ushort* __restrict__ v_t, int K)
{
    __shared__ ushort At[2][128 * 64];   // 2 x 16 KB
    __shared__ ushort Bt[2][128 * 64];   // 2 x 16 KB
    const int tid  = threadIdx.x;
    const int wave = tid >> 6, lane = tid & 63;
    // m204 bijective XCD swizzle of the 756-block grid (x fastest)
    const int lid  = blockIdx.y * 21 + blockIdx.x;
    const int xcd  = lid & 7, pos = lid >> 3;
    const int wgid = (xcd < 4 ? xcd * 95 : 4 * 95 + (xcd - 4) * 94) + pos;
    const int m0 = (wgid % 21) * 128, n0 = (wgid / 21) * 128;
    const int wr = wave >> 1, wc = wave & 1;
    const int r = lane & 15, g = lane >> 4;
    const int swz = r & 7;
    const int sj_row[4] = { (0*256+tid)>>3, (1*256+tid)>>3,
                            (2*256+tid)>>3, (3*256+tid)>>3 };
    const int sj_w = tid & 7;

    f32x4 acc[4][4] = {};
    const int NT = K >> 6;   // 24

#define STAGE_G(buf, kb)                                                      \
    do {                                                                      \
        const ushort* Ag = A + (size_t)m0 * K + (kb);                         \
        const ushort* Bg = B + (size_t)n0 * K + (kb);                         \
        _Pragma("unroll")                                                     \
        for (int t = 0; t < 4; ++t) {                                         \
            int row = sj_row[t];                                              \
            GLOAD16(Ag + (size_t)row * K + ((sj_w ^ (row & 7)) * 8),          \
                    &At[buf][(t*256 + tid) * 8]);                             \
        }                                                                     \
        _Pragma("unroll")                                                     \
        for (int t = 0; t < 4; ++t) {                                         \
            int row = sj_row[t];                                              \
            GLOAD16(Bg + (size_t)row * K + ((sj_w ^ (row & 7)) * 8),          \
                    &Bt[buf][(t*256 + tid) * 8]);                             \
        }                                                                     \
    } while (0)

    STAGE_G(0, 0);
    asm volatile("s_waitcnt vmcnt(0)" ::: "memory");
    __syncthreads();

    int cur = 0;
    for (int kt = 0; kt < NT; ++kt) {
        if (kt + 1 < NT) STAGE_G(cur ^ 1, (kt+1) * 64);
#pragma unroll
        for (int kk = 0; kk < 2; ++kk) {
            bf16x8 af[4], bfr[4];
#pragma unroll
            for (int i = 0; i < 4; ++i)
                af[i] = *reinterpret_cast<const bf16x8*>(
                    &At[cur][(wr*64 + i*16 + r) * 64 + ((kk*4 + g) ^ swz) * 8]);
#pragma unroll
            for (int i = 0; i < 4; ++i)
                bfr[i] = *reinterpret_cast<const bf16x8*>(
                    &Bt[cur][(wc*64 + i*16 + r) * 64 + ((kk*4 + g) ^ swz) * 8]);
#pragma unroll
            for (int mi = 0; mi < 4; ++mi)
#pragma unroll
                for (int ni = 0; ni < 4; ++ni)
                    acc[mi][ni] = __builtin_amdgcn_mfma_f32_16x16x32_bf16(
                        af[mi], bfr[ni], acc[mi][ni], 0, 0, 0);
        }
        if (kt + 1 < NT) {
            asm volatile("s_waitcnt vmcnt(0)" ::: "memory");
            __syncthreads();
            cur ^= 1;
        }
    }
#undef STAGE_G

    if (n0 < 2*DIM) {       // q/k region (block-uniform branch)
#pragma unroll
        for (int ni = 0; ni < 4; ++ni) {
            int col = n0 + wc*64 + ni*16 + r;
            float bias = (col < DIM) ? bq[col] : bk[col - DIM];
#pragma unroll
            for (int mi = 0; mi < 4; ++mi) {
                int row = m0 + wr*64 + mi*16 + g*4;
#pragma unroll
                for (int j = 0; j < 4; ++j)
                    qkb[(size_t)(row + j) * (2*DIM) + col] =
                        f2bf(acc[mi][ni][j] + bias);
            }
        }
    } else {                // V region: transposed 8B stores into v_t[d][s]
#pragma unroll
        for (int ni = 0; ni < 4; ++ni) {
            int d = n0 - 2*DIM + wc*64 + ni*16 + r;
            float bias = bv[d];
#pragma unroll
            for (int mi = 0; mi < 4; ++mi) {
                int row = m0 + wr*64 + mi*16 + g*4;
                uint2 pkt;
                pkt.x = cvtpk(acc[mi][ni][0] + bias, acc[mi][ni][1] + bias);
                pkt.y = cvtpk(acc[mi][ni][2] + bias, acc[mi][ni][3] + bias);
                *reinterpret_cast<uint2*>(&v_t[(size_t)d * S_LEN + row]) = pkt;
            }
        }
    }
}

// ---------------------------------------------------------------------------
// 2b) out-projection GEMM (R17-verified): BM=128, BN=64, dbuf + XOR swizzle.
// ---------------------------------------------------------------------------
__global__ __launch_bounds__(256) void gemm_bt2(
    const ushort* __restrict__ A, const ushort* __restrict__ B,
    const float* __restrict__ b0,
    float* __restrict__ C, int M, int N, int K)
{
    __shared__ ushort At[2][128 * 64];   // 2 x 16 KB
    __shared__ ushort Bt[2][64 * 64];    // 2 x  8 KB
    const int tid  = threadIdx.x;
    const int wave = tid >> 6, lane = tid & 63;
    const int m0 = blockIdx.x * 128, n0 = blockIdx.y * 64;
    const int wr = wave >> 1, wc = wave & 1;
    const int r = lane & 15, g = lane >> 4;
    const int swz = r & 7;
    const int sj_row[4] = { (0*256+tid)>>3, (1*256+tid)>>3,
                            (2*256+tid)>>3, (3*256+tid)>>3 };
    const int sj_w = tid & 7;

    f32x4 acc[4][2] = {};
    const int NT = K >> 6;   // 24

#define STAGE_G2(buf, kb)                                                     \
    do {                                                                      \
        const ushort* Ag = A + (size_t)m0 * K + (kb);                         \
        const ushort* Bg = B + (size_t)n0 * K + (kb);                         \
        _Pragma("unroll")                                                     \
        for (int t = 0; t < 4; ++t) {                                         \
            int row = sj_row[t];                                              \
            GLOAD16(Ag + (size_t)row * K + ((sj_w ^ (row & 7)) * 8),          \
                    &At[buf][(t*256 + tid) * 8]);                             \
        }                                                                     \
        _Pragma("unroll")                                                     \
        for (int t = 0; t < 2; ++t) {                                         \
            int row = sj_row[t];                                              \
            GLOAD16(Bg + (size_t)row * K + ((sj_w ^ (row & 7)) * 8),          \
                    &Bt[buf][(t*256 + tid) * 8]);                             \
        }                                                                     \
    } while (0)

    STAGE_G2(0, 0);
    asm volatile("s_waitcnt vmcnt(0)" ::: "memory");
    __syncthreads();

    int cur = 0;
    for (int kt = 0; kt < NT; ++kt) {
        if (kt + 1 < NT) STAGE_G2(cur ^ 1, (kt+1) * 64);
#pragma unroll
        for (int kk = 0; kk < 2; ++kk) {
            bf16x8 af[4], bfr[2];
#pragma unroll
            for (int i = 0; i < 4; ++i)
                af[i] = *reinterpret_cast<const bf16x8*>(
                    &At[cur][(wr*64 + i*16 + r) * 64 + ((kk*4 + g) ^ swz) * 8]);
#pragma unroll
            for (int i = 0; i < 2; ++i)
                bfr[i] = *reinterpret_cast<const bf16x8*>(
                    &Bt[cur][(wc*32 + i*16 + r) * 64 + ((kk*4 + g) ^ swz) * 8]);
#pragma unroll
            for (int mi = 0; mi < 4; ++mi)
#pragma unroll
                for (int ni = 0; ni < 2; ++ni)
                    acc[mi][ni] = __builtin_amdgcn_mfma_f32_16x16x32_bf16(
                        af[mi], bfr[ni], acc[mi][ni], 0, 0, 0);
        }
        if (kt + 1 < NT) {
            asm volatile("s_waitcnt vmcnt(0)" ::: "memory");
            __syncthreads();
            cur ^= 1;
        }
    }
#undef STAGE_G2

#pragma unroll
    for (int ni = 0; ni < 2; ++ni) {
        int col = n0 + wc*32 + ni*16 + r;
        float bias = b0[col];
#pragma unroll
        for (int mi = 0; mi < 4; ++mi) {
            int row = m0 + wr*64 + mi*16 + g*4;
#pragma unroll
            for (int j = 0; j < 4; ++j)
                C[(size_t)(row + j) * N + col] = acc[mi][ni][j] + bias;
        }
    }
}

// ---------------------------------------------------------------------------
// 3) RMS-norm + RoPE, R18: ONE WAVE PER ROW (4 rows/block, grid 672).
//    16B uint4 loads (3/lane), pure shfl_xor reduction (no LDS/barriers),
//    16B uint4 packed stores (head is lane-uniform: lane*4+e never crosses
//    a 64-pair boundary). 1/sqrt(D)*log2(e) folded into q (exp2 softmax).
// ---------------------------------------------------------------------------
__global__ __launch_bounds__(256) void normrope(
    const ushort* __restrict__ qkb, const int* __restrict__ gsz,
    const float* __restrict__ gq, const float* __restrict__ gk,
    const float* __restrict__ fcos, const float* __restrict__ fsin,
    ushort* __restrict__ q_r, ushort* __restrict__ k_r)
{
    const int wave = threadIdx.x >> 6, lane = threadIdx.x & 63;
    const int s = blockIdx.x * 4 + wave;
    const uint4* qrow = reinterpret_cast<const uint4*>(qkb + (size_t)s * (2*DIM));
    const uint4* krow = reinterpret_cast<const uint4*>(qkb + (size_t)s * (2*DIM) + DIM);

    uint4 qv[3], kv[3];
    float sq = 0.f, sk = 0.f;
#pragma unroll
    for (int t = 0; t < 3; ++t) {
        qv[t] = qrow[t*64 + lane];
        kv[t] = krow[t*64 + lane];
        const uint* qu = reinterpret_cast<const uint*>(&qv[t]);
        const uint* ku = reinterpret_cast<const uint*>(&kv[t]);
#pragma unroll
        for (int e = 0; e < 4; ++e) {
            float a = bf2f(qu[e] & 0xffffu), b = bf2f(qu[e] >> 16);
            sq += a*a + b*b;
            a = bf2f(ku[e] & 0xffffu); b = bf2f(ku[e] >> 16);
            sk += a*a + b*b;
        }
    }
#pragma unroll
    for (int off = 1; off < 64; off <<= 1) {
        sq += __shfl_xor(sq, off);
        sk += __shfl_xor(sk, off);
    }
    const float rmsq = rsqrtf(sq * (1.f/DIM) + 1e-6f);
    const float rmsk = rsqrtf(sk * (1.f/DIM) + 1e-6f);

    const int hh = gsz[1], ww = gsz[2];
    const int fidx = s / (hh*ww), rem = s % (hh*ww);
    const int hidx = rem / ww,  widx = rem % ww;
    // fold 1/sqrt(128) * log2(e): softmax runs in exp2 domain
    const float qscale = rmsq * (0.08838834764831845f * 1.4426950408889634f);

    const int c0 = (lane*4) & 63;
    const int hbase = (lane*4) >> 6;   // 0..3, constant across e
#pragma unroll
    for (int t = 0; t < 3; ++t) {
        const uint* qu = reinterpret_cast<const uint*>(&qv[t]);
        const uint* ku = reinterpret_cast<const uint*>(&kv[t]);
        uint4 qo, ko;
        uint* qop = reinterpret_cast<uint*>(&qo);
        uint* kop = reinterpret_cast<uint*>(&ko);
        const int head = t*4 + hbase;
#pragma unroll
        for (int e = 0; e < 4; ++e) {
            int c = c0 + e;
            int coord = (c < 22) ? fidx : (c < 43) ? hidx : widx;
            float cv = fcos[coord*64 + c], sv = fsin[coord*64 + c];
            int p = t*256 + lane*4 + e;
            float2 gqv = reinterpret_cast<const float2*>(gq)[p];
            float2 gkv = reinterpret_cast<const float2*>(gk)[p];
            float a = bf2f(qu[e] & 0xffffu) * qscale * gqv.x;
            float b = bf2f(qu[e] >> 16)     * qscale * gqv.y;
            qop[e] = cvtpk(a*cv - b*sv, a*sv + b*cv);
            a = bf2f(ku[e] & 0xffffu) * rmsk * gkv.x;
            b = bf2f(ku[e] >> 16)     * rmsk * gkv.y;
            kop[e] = cvtpk(a*cv - b*sv, a*sv + b*cv);
        }
        size_t off4 = (((size_t)head * S_LEN + s) * 64 + c0) >> 2;  // uint4 idx
        reinterpret_cast<uint4*>(q_r)[off4] = qo;
        reinterpret_cast<uint4*>(k_r)[off4] = ko;
    }
}

// ---------------------------------------------------------------------------
// 5) Flash attention, 32x32x16 MFMA with KEY-SPLIT wave pairs (R14-verified)
//    + R18: T5 setprio(1) around both MFMA clusters (m191 attn precedent).
//    waves {2p,2p+1} share q-rows; wave khalf=w&1 handles keys
//    [kt*64+khalf*32, +32). P in-register (cvt_pk + permlane32_swap).
//    End merge via freed Kl/Vl space. K+V staged dbuf w/ XOR chunk swizzle.
//    NOTE: V-direct-to-reg attempted twice (R10/R12) — compiler-defeated.
// ---------------------------------------------------------------------------
__global__ __launch_bounds__(256) void attn_fwd(
    const ushort* __restrict__ q_r, const ushort* __restrict__ k_r,
    const ushort* __restrict__ v_t, const int* __restrict__ seq_lens,
    ushort* __restrict__ attn_out)
{
    __shared__ ushort Kl[2][64 * 128];   // 2 x 16 KB (reused as merge Obuf)
    __shared__ ushort Vl[2][128 * 64];   // 2 x 16 KB (reused as merge MLbuf)
    const int tid  = threadIdx.x;
    const int wave = tid >> 6, lane = tid & 63;
    const int n  = blockIdx.y;
    const int seq = seq_lens[0];
    const int khalf = wave & 1, pair = wave >> 1;
    const int ql = lane & 31, h = lane >> 5, sw = lane & 7;
    const int qrow = blockIdx.x * 64 + pair * 32 + ql;
    const ushort* Qh = q_r + (size_t)n * S_LEN * HD;
    const ushort* Kh = k_r + (size_t)n * S_LEN * HD;
    const ushort* Vh = v_t + (size_t)n * HD * S_LEN;

    const int kj_row[4] = { (0*256+tid)>>4, (1*256+tid)>>4, (2*256+tid)>>4, (3*256+tid)>>4 };
    const int kj_w  = tid & 15;
    const int vj_d[4]  = { (0*256+tid)>>3, (1*256+tid)>>3, (2*256+tid)>>3, (3*256+tid)>>3 };
    const int vj_w  = tid & 7;

    bf16x8 qf[8];   // Q[qrow][c*16 + h*8 ..+7] (B-frag: col=q=ql, k=h*8+e)
#pragma unroll
    for (int c = 0; c < 8; ++c)
        qf[c] = *reinterpret_cast<const bf16x8*>(Qh + (size_t)qrow * HD + c*16 + h*8);

    f32x16 oacc[4] = {};   // oacc[db][j] = O[d=db*32+(j&3)+8*(j>>2)+4h][q=ql]
    float mrun = -1e30f, lrun = 0.f;

    const int nt = (seq + 63) >> 6;

#define STAGE(buf, kbase)                                                     \
    do {                                                                      \
        _Pragma("unroll")                                                     \
        for (int t = 0; t < 4; ++t) {                                         \
            int row = kj_row[t];                                              \
            GLOAD16(Kh + (size_t)((kbase) + row) * HD + ((kj_w ^ (row & 7)) * 8), \
                    &Kl[buf][(t*256 + wave*64) * 8]);                         \
        }                                                                     \
        _Pragma("unroll")                                                     \
        for (int t = 0; t < 4; ++t) {                                         \
            int d = vj_d[t];                                                  \
            GLOAD16(Vh + (size_t)d * S_LEN + (kbase) + ((vj_w ^ (d & 7)) * 8), \
                    &Vl[buf][(t*256 + wave*64) * 8]);                         \
        }                                                                     \
    } while (0)

    STAGE(0, 0);
    asm volatile("s_waitcnt vmcnt(0)" ::: "memory");
    __syncthreads();

    int cur = 0;
    for (int kt = 0; kt < nt; ++kt) {
        const int k0 = kt * 64 + khalf * 32;   // this wave's 32-key block
        if (kt + 1 < nt) STAGE(cur ^ 1, (kt+1) * 64);

        // ---- QK^T swapped (32x32x16): sf[j] = S[key=k0+(j&3)+8*(j>>2)+4h][q=ql]
        f32x16 sf = {};
        const ushort* kl = &Kl[cur][(khalf*32 + ql) * 128];
        __builtin_amdgcn_s_setprio(1);
#pragma unroll
        for (int c = 0; c < 8; ++c)
            sf = __builtin_amdgcn_mfma_f32_32x32x16_bf16(
                *reinterpret_cast<const bf16x8*>(kl + ((2*c + h) ^ sw) * 8),
                qf[c], sf, 0, 0, 0);
        __builtin_amdgcn_s_setprio(0);
        if (k0 + 32 > seq) {   // safety mask (S divisible by 64)
#pragma unroll
            for (int j = 0; j < 16; ++j)
                if (k0 + (j&3) + 8*(j>>2) + 4*h >= seq) sf[j] = -1e30f;
        }
        // ---- row max: 15-op in-lane tree + 1 shfl (combine h-halves)
        float pm = sf[0];
#pragma unroll
        for (int j = 1; j < 16; ++j) pm = fmaxf(pm, sf[j]);
        pm = fmaxf(pm, __shfl_xor(pm, 32));
        // ---- defer-max (THR=8, log2 domain)
        if (!__all(pm - mrun <= 8.f)) {
            float mn = fmaxf(mrun, pm);
            float scl = fexp2(mrun - mn);
            mrun = mn;
            lrun *= scl;
#pragma unroll
            for (int db = 0; db < 4; ++db)
#pragma unroll
                for (int j = 0; j < 16; ++j) oacc[db][j] *= scl;
        }
        // ---- P = exp2(S - mrun), in-lane sum + 1 shfl
        float ps = 0.f;
#pragma unroll
        for (int j = 0; j < 16; ++j) {
            float e = fexp2(sf[j] - mrun);
            sf[j] = e;
            ps += e;
        }
        ps += __shfl_xor(ps, 32);
        lrun += ps;
        // ---- P -> bf16 B-frags in-register (cvt_pk + permlane32_swap, R7)
        uint u0 = cvtpk(sf[0],  sf[1]),  u1 = cvtpk(sf[2],  sf[3]);
        uint u2 = cvtpk(sf[4],  sf[5]),  u3 = cvtpk(sf[6],  sf[7]);
        uint u4 = cvtpk(sf[8],  sf[9]),  u5 = cvtpk(sf[10], sf[11]);
        uint u6 = cvtpk(sf[12], sf[13]), u7 = cvtpk(sf[14], sf[15]);
        asm("v_permlane32_swap_b32 %0, %1" : "+v"(u0), "+v"(u2));
        asm("v_permlane32_swap_b32 %0, %1" : "+v"(u1), "+v"(u3));
        asm("v_permlane32_swap_b32 %0, %1" : "+v"(u4), "+v"(u6));
        asm("v_permlane32_swap_b32 %0, %1" : "+v"(u5), "+v"(u7));
        union { uint uu[4]; bf16x8 v; } fa, fb;
        fa.uu[0] = u0; fa.uu[1] = u1; fa.uu[2] = u2; fa.uu[3] = u3; // keys 0..15
        fb.uu[0] = u4; fb.uu[1] = u5; fb.uu[2] = u6; fb.uu[3] = u7; // keys 16..31
        // ---- PV swapped: oacc[db] += mfma(V_frag, P_frag) -> O[d][q]
        __builtin_amdgcn_s_setprio(1);
#pragma unroll
        for (int db = 0; db < 4; ++db) {
            const ushort* vl = &Vl[cur][(db*32 + ql) * 64];
            oacc[db] = __builtin_amdgcn_mfma_f32_32x32x16_bf16(
                *reinterpret_cast<const bf16x8*>(vl + ((khalf*4 + 0 + h) ^ sw) * 8),
                fa.v, oacc[db], 0, 0, 0);
            oacc[db] = __builtin_amdgcn_mfma_f32_32x32x16_bf16(
                *reinterpret_cast<const bf16x8*>(vl + ((khalf*4 + 2 + h) ^ sw) * 8),
                fb.v, oacc[db], 0, 0, 0);
        }
        __builtin_amdgcn_s_setprio(0);

        if (kt + 1 < nt) {
            asm volatile("s_waitcnt vmcnt(0)" ::: "memory");
            __syncthreads();
            cur ^= 1;
        }
    }
#undef STAGE

    // ---- merge the two key-halves of each wave pair via freed LDS
    __syncthreads();
    float* Obuf  = (float*)&Kl[0][0];   // [2 pairs][128 d][32 q] = 8192 f32
    float* MLbuf = (float*)&Vl[0][0];   // [2 pairs][{m,l}][32 q]
    if (khalf == 1) {
#pragma unroll
        for (int db = 0; db < 4; ++db)
#pragma unroll
            for (int j = 0; j < 16; ++j) {
                int d = db*32 + (j&3) + 8*(j>>2) + 4*h;
                Obuf[pair*4096 + d*32 + ql] = oacc[db][j];
            }
        if (h == 0) { MLbuf[pair*64 + ql] = mrun; MLbuf[pair*64 + 32 + ql] = lrun; }
    }
    __syncthreads();
    if (khalf == 0) {
        float m2 = MLbuf[pair*64 + ql], l2 = MLbuf[pair*64 + 32 + ql];
        float mm = fmaxf(mrun, m2);
        float s1 = fexp2(mrun - mm), s2 = fexp2(m2 - mm);
        float ltot = lrun * s1 + l2 * s2;
        float inv = (ltot > 0.f) ? 1.f / ltot : 0.f;
#pragma unroll
        for (int db = 0; db < 4; ++db)
#pragma unroll
            for (int j = 0; j < 16; ++j) {
                int d = db*32 + (j&3) + 8*(j>>2) + 4*h;
                oacc[db][j] = (oacc[db][j] * s1 +
                               Obuf[pair*4096 + d*32 + ql] * s2) * inv;
            }
        // store 16x b64: d = db*32 + 8*jg + 4h + (0..3), row qrow
#pragma unroll
        for (int db = 0; db < 4; ++db)
#pragma unroll
            for (int jg = 0; jg < 4; ++jg) {
                uint2 pkt;
                pkt.x = cvtpk(oacc[db][jg*4+0], oacc[db][jg*4+1]);
                pkt.y = cvtpk(oacc[db][jg*4+2], oacc[db][jg*4+3]);
                *reinterpret_cast<uint2*>(
                    &attn_out[(size_t)qrow * DIM + n*HD + db*32 + jg*8 + 4*h]) = pkt;
            }
    }
}

// ---------------------------------------------------------------------------
extern "C" void kernel_launch(void* const* d_in, const int* in_sizes, int n_in,
                              void* d_out, int out_size, void* d_ws, size_t ws_size,
                              hipStream_t stream)
{
    const float* x    = (const float*)d_in[0];
    const int*   seqL = (const int*)  d_in[1];
    const int*   gsz  = (const int*)  d_in[2];
    const float* fcos = (const float*)d_in[3];
    const float* fsin = (const float*)d_in[4];
    const float* Wq   = (const float*)d_in[5];
    const float* bq   = (const float*)d_in[6];
    const float* Wk   = (const float*)d_in[7];
    const float* bk   = (const float*)d_in[8];
    const float* Wv   = (const float*)d_in[9];
    const float* bv   = (const float*)d_in[10];
    const float* Wo   = (const float*)d_in[11];
    const float* bo   = (const float*)d_in[12];
    const float* gq   = (const float*)d_in[13];
    const float* gk   = (const float*)d_in[14];
    float* out = (float*)d_out;

    char* ws = (char*)d_ws;
    ushort* xb  = (ushort*)ws;                     // S*DIM         =  8.26 MB
    ushort* wb  = xb  + (size_t)S_LEN * DIM;       // 4*DIM*DIM     = 18.87 MB
    ushort* qkb = wb  + 4*(size_t)DIM*DIM;         // S*3072        = 16.52 MB
    ushort* v_t = qkb + (size_t)S_LEN * 2*DIM;     // DIM*S         =  8.26 MB
    ushort* q_r = v_t + (size_t)DIM * S_LEN;       // S*DIM         =  8.26 MB
    ushort* k_r = q_r + (size_t)S_LEN * DIM;       // S*DIM         =  8.26 MB
    ushort* ao  = k_r + (size_t)S_LEN * DIM;       // S*DIM         =  8.26 MB
    // total ws use: ~76.7 MB

    convert_all<<<13248, 256, 0, stream>>>(x, Wq, Wk, Wv, Wo, xb, wb);
    gemm_qkv<<<dim3(21, 36), 256, 0, stream>>>(xb, wb, bq, bk, bv,
                                               qkb, v_t, DIM);
    normrope<<<672, 256, 0, stream>>>(qkb, gsz, gq, gk, fcos, fsin, q_r, k_r);
    attn_fwd<<<dim3(42, 12), 256, 0, stream>>>(q_r, k_r, v_t, seqL, ao);
    gemm_bt2<<<dim3(21, 24), 256, 0, stream>>>(ao, wb + 3*(size_t)DIM*DIM,
                                               bo, out, S_LEN, DIM, DIM);
}

// Round 22
// 187.237 us; speedup vs baseline: 1.0130x; 1.0130x over previous
//
#include <hip/hip_runtime.h>
#include <hip/hip_bf16.h>
#include <stdint.h>

#define S_LEN 2688
#define DIM   1536
#define NH    12
#define HD    128
#define QKV_N 4608   // 3*DIM

typedef __attribute__((ext_vector_type(8)))  short bf16x8;
typedef __attribute__((ext_vector_type(4)))  float f32x4;
typedef __attribute__((ext_vector_type(16))) float f32x16;

__device__ inline ushort f2bf(float f) {
    uint32_t u = __float_as_uint(f);
    uint32_t r = (u + 0x7fffu + ((u >> 16) & 1u)) >> 16;
    return (ushort)r;
}
__device__ inline float bf2f(uint u) { return __uint_as_float(u << 16); }
__device__ inline float fexp2(float x) {           // raw v_exp_f32 (2^x); args
    float r;                                       // bounded by defer-max
    asm("v_exp_f32 %0, %1" : "=v"(r) : "v"(x));
    return r;
}
__device__ inline uint cvtpk(float lo, float hi) { // 2xf32 -> packed bf16
    uint r;
    asm("v_cvt_pk_bf16_f32 %0, %1, %2" : "=v"(r) : "v"(lo), "v"(hi));
    return r;
}

#define GLOAD16(gp, lp) __builtin_amdgcn_global_load_lds( \
    (__attribute__((address_space(1))) const void*)(gp),  \
    (__attribute__((address_space(3))) void*)(lp), 16, 0, 0)

// ---------------------------------------------------------------------------
// 1) fp32 -> bf16 convert: x and the four weight matrices (fused into wb)
// ---------------------------------------------------------------------------
__global__ __launch_bounds__(256) void convert_all(
    const float* __restrict__ x,
    const float* __restrict__ wq, const float* __restrict__ wk,
    const float* __restrict__ wv, const float* __restrict__ wo,
    ushort* __restrict__ xb, ushort* __restrict__ wb)
{
    const size_t NX4 = (size_t)S_LEN * DIM / 4;   // 1,032,192
    const size_t NW4 = (size_t)DIM * DIM / 4;     //   589,824
    size_t i = (size_t)blockIdx.x * 256 + threadIdx.x;
    const float* src; ushort* dst;
    if (i < NX4)            { src = x;  dst = xb; }
    else if (i < NX4+1*NW4) { src = wq; dst = wb;                        i -= NX4; }
    else if (i < NX4+2*NW4) { src = wk; dst = wb + 1*(size_t)DIM*DIM;    i -= NX4+1*NW4; }
    else if (i < NX4+3*NW4) { src = wv; dst = wb + 2*(size_t)DIM*DIM;    i -= NX4+2*NW4; }
    else if (i < NX4+4*NW4) { src = wo; dst = wb + 3*(size_t)DIM*DIM;    i -= NX4+3*NW4; }
    else return;
    float4 v = reinterpret_cast<const float4*>(src)[i];
    ushort4 o = { f2bf(v.x), f2bf(v.y), f2bf(v.z), f2bf(v.w) };
    reinterpret_cast<ushort4*>(dst)[i] = o;
}

// ---------------------------------------------------------------------------
// 2) QKV GEMM (R15-verified): bf16 out, q/k -> qkb [S][3072];
//    V -> v_t [d][S] transposed. Dbuf staging + both-sides XOR chunk swizzle
//    + XCD remap. A/B history: swizzle ~ -12 µs, dbuf ~ -4.4 µs (R15/R16).
// ---------------------------------------------------------------------------
__global__ __launch_bounds__(256) void gemm_qkv(
    const ushort* __restrict__ A, const ushort* __restrict__ B,
    const float* __restrict__ bq, const float* __restrict__ bk,
    const float* __restrict__ bv,
    ushort* __restrict__ qkb, ushort* __restrict__ v_t, int K)
{
    __shared__ ushort At[2][128 * 64];   // 2 x 16 KB
    __shared__ ushort Bt[2][128 * 64];   // 2 x 16 KB
    const int tid  = threadIdx.x;
    const int wave = tid >> 6, lane = tid & 63;
    // m204 bijective XCD swizzle of the 756-block grid (x fastest)
    const int lid  = blockIdx.y * 21 + blockIdx.x;
    const int xcd  = lid & 7, pos = lid >> 3;
    const int wgid = (xcd < 4 ? xcd * 95 : 4 * 95 + (xcd - 4) * 94) + pos;
    const int m0 = (wgid % 21) * 128, n0 = (wgid / 21) * 128;
    const int wr = wave >> 1, wc = wave & 1;
    const int r = lane & 15, g = lane >> 4;
    const int swz = r & 7;
    const int sj_row[4] = { (0*256+tid)>>3, (1*256+tid)>>3,
                            (2*256+tid)>>3, (3*256+tid)>>3 };
    const int sj_w = tid & 7;

    f32x4 acc[4][4] = {};
    const int NT = K >> 6;   // 24

#define STAGE_G(buf, kb)                                                      \
    do {                                                                      \
        const ushort* Ag = A + (size_t)m0 * K + (kb);                         \
        const ushort* Bg = B + (size_t)n0 * K + (kb);                         \
        _Pragma("unroll")                                                     \
        for (int t = 0; t < 4; ++t) {                                         \
            int row = sj_row[t];                                              \
            GLOAD16(Ag + (size_t)row * K + ((sj_w ^ (row & 7)) * 8),          \
                    &At[buf][(t*256 + tid) * 8]);                             \
        }                                                                     \
        _Pragma("unroll")                                                     \
        for (int t = 0; t < 4; ++t) {                                         \
            int row = sj_row[t];                                              \
            GLOAD16(Bg + (size_t)row * K + ((sj_w ^ (row & 7)) * 8),          \
                    &Bt[buf][(t*256 + tid) * 8]);                             \
        }                                                                     \
    } while (0)

    STAGE_G(0, 0);
    asm volatile("s_waitcnt vmcnt(0)" ::: "memory");
    __syncthreads();

    int cur = 0;
    for (int kt = 0; kt < NT; ++kt) {
        if (kt + 1 < NT) STAGE_G(cur ^ 1, (kt+1) * 64);
#pragma unroll
        for (int kk = 0; kk < 2; ++kk) {
            bf16x8 af[4], bfr[4];
#pragma unroll
            for (int i = 0; i < 4; ++i)
                af[i] = *reinterpret_cast<const bf16x8*>(
                    &At[cur][(wr*64 + i*16 + r) * 64 + ((kk*4 + g) ^ swz) * 8]);
#pragma unroll
            for (int i = 0; i < 4; ++i)
                bfr[i] = *reinterpret_cast<const bf16x8*>(
                    &Bt[cur][(wc*64 + i*16 + r) * 64 + ((kk*4 + g) ^ swz) * 8]);
#pragma unroll
            for (int mi = 0; mi < 4; ++mi)
#pragma unroll
                for (int ni = 0; ni < 4; ++ni)
                    acc[mi][ni] = __builtin_amdgcn_mfma_f32_16x16x32_bf16(
                        af[mi], bfr[ni], acc[mi][ni], 0, 0, 0);
        }
        if (kt + 1 < NT) {
            asm volatile("s_waitcnt vmcnt(0)" ::: "memory");
            __syncthreads();
            cur ^= 1;
        }
    }
#undef STAGE_G

    if (n0 < 2*DIM) {       // q/k region (block-uniform branch)
#pragma unroll
        for (int ni = 0; ni < 4; ++ni) {
            int col = n0 + wc*64 + ni*16 + r;
            float bias = (col < DIM) ? bq[col] : bk[col - DIM];
#pragma unroll
            for (int mi = 0; mi < 4; ++mi) {
                int row = m0 + wr*64 + mi*16 + g*4;
#pragma unroll
                for (int j = 0; j < 4; ++j)
                    qkb[(size_t)(row + j) * (2*DIM) + col] =
                        f2bf(acc[mi][ni][j] + bias);
            }
        }
    } else {                // V region: transposed 8B stores into v_t[d][s]
#pragma unroll
        for (int ni = 0; ni < 4; ++ni) {
            int d = n0 - 2*DIM + wc*64 + ni*16 + r;
            float bias = bv[d];
#pragma unroll
            for (int mi = 0; mi < 4; ++mi) {
                int row = m0 + wr*64 + mi*16 + g*4;
                uint2 pkt;
                pkt.x = cvtpk(acc[mi][ni][0] + bias, acc[mi][ni][1] + bias);
                pkt.y = cvtpk(acc[mi][ni][2] + bias, acc[mi][ni][3] + bias);
                *reinterpret_cast<uint2*>(&v_t[(size_t)d * S_LEN + row]) = pkt;
            }
        }
    }
}

// ---------------------------------------------------------------------------
// 2b) out-projection GEMM (R17-verified): BM=128, BN=64, dbuf + XOR swizzle.
// ---------------------------------------------------------------------------
__global__ __launch_bounds__(256) void gemm_bt2(
    const ushort* __restrict__ A, const ushort* __restrict__ B,
    const float* __restrict__ b0,
    float* __restrict__ C, int M, int N, int K)
{
    __shared__ ushort At[2][128 * 64];   // 2 x 16 KB
    __shared__ ushort Bt[2][64 * 64];    // 2 x  8 KB
    const int tid  = threadIdx.x;
    const int wave = tid >> 6, lane = tid & 63;
    const int m0 = blockIdx.x * 128, n0 = blockIdx.y * 64;
    const int wr = wave >> 1, wc = wave & 1;
    const int r = lane & 15, g = lane >> 4;
    const int swz = r & 7;
    const int sj_row[4] = { (0*256+tid)>>3, (1*256+tid)>>3,
                            (2*256+tid)>>3, (3*256+tid)>>3 };
    const int sj_w = tid & 7;

    f32x4 acc[4][2] = {};
    const int NT = K >> 6;   // 24

#define STAGE_G2(buf, kb)                                                     \
    do {                                                                      \
        const ushort* Ag = A + (size_t)m0 * K + (kb);                         \
        const ushort* Bg = B + (size_t)n0 * K + (kb);                         \
        _Pragma("unroll")                                                     \
        for (int t = 0; t < 4; ++t) {                                         \
            int row = sj_row[t];                                              \
            GLOAD16(Ag + (size_t)row * K + ((sj_w ^ (row & 7)) * 8),          \
                    &At[buf][(t*256 + tid) * 8]);                             \
        }                                                                     \
        _Pragma("unroll")                                                     \
        for (int t = 0; t < 2; ++t) {                                         \
            int row = sj_row[t];                                              \
            GLOAD16(Bg + (size_t)row * K + ((sj_w ^ (row & 7)) * 8),          \
                    &Bt[buf][(t*256 + tid) * 8]);                             \
        }                                                                     \
    } while (0)

    STAGE_G2(0, 0);
    asm volatile("s_waitcnt vmcnt(0)" ::: "memory");
    __syncthreads();

    int cur = 0;
    for (int kt = 0; kt < NT; ++kt) {
        if (kt + 1 < NT) STAGE_G2(cur ^ 1, (kt+1) * 64);
#pragma unroll
        for (int kk = 0; kk < 2; ++kk) {
            bf16x8 af[4], bfr[2];
#pragma unroll
            for (int i = 0; i < 4; ++i)
                af[i] = *reinterpret_cast<const bf16x8*>(
                    &At[cur][(wr*64 + i*16 + r) * 64 + ((kk*4 + g) ^ swz) * 8]);
#pragma unroll
            for (int i = 0; i < 2; ++i)
                bfr[i] = *reinterpret_cast<const bf16x8*>(
                    &Bt[cur][(wc*32 + i*16 + r) * 64 + ((kk*4 + g) ^ swz) * 8]);
#pragma unroll
            for (int mi = 0; mi < 4; ++mi)
#pragma unroll
                for (int ni = 0; ni < 2; ++ni)
                    acc[mi][ni] = __builtin_amdgcn_mfma_f32_16x16x32_bf16(
                        af[mi], bfr[ni], acc[mi][ni], 0, 0, 0);
        }
        if (kt + 1 < NT) {
            asm volatile("s_waitcnt vmcnt(0)" ::: "memory");
            __syncthreads();
            cur ^= 1;
        }
    }
#undef STAGE_G2

#pragma unroll
    for (int ni = 0; ni < 2; ++ni) {
        int col = n0 + wc*32 + ni*16 + r;
        float bias = b0[col];
#pragma unroll
        for (int mi = 0; mi < 4; ++mi) {
            int row = m0 + wr*64 + mi*16 + g*4;
#pragma unroll
            for (int j = 0; j < 4; ++j)
                C[(size_t)(row + j) * N + col] = acc[mi][ni][j] + bias;
        }
    }
}

// ---------------------------------------------------------------------------
// 3) RMS-norm + RoPE for q,k from bf16 qkb; writes head-major bf16 [n][s][d].
//    1/sqrt(D)*log2(e) folded into q (exp2-domain softmax downstream).
//    (R17 version; R18's wave-per-row rewrite regressed, reverted.)
// ---------------------------------------------------------------------------
__global__ __launch_bounds__(256) void normrope(
    const ushort* __restrict__ qkb, const int* __restrict__ gsz,
    const float* __restrict__ gq, const float* __restrict__ gk,
    const float* __restrict__ fcos, const float* __restrict__ fsin,
    ushort* __restrict__ q_r, ushort* __restrict__ k_r)
{
    const int s   = blockIdx.x;
    const int tid = threadIdx.x;
    const int wave = tid >> 6, lane = tid & 63;
    const uint* qrow = reinterpret_cast<const uint*>(qkb + (size_t)s * (2*DIM));
    const uint* krow = qrow + DIM/2;   // 768 uints = 1536 bf16

    float2 qv[3], kv[3];
    float sq = 0.f, sk = 0.f;
#pragma unroll
    for (int i = 0; i < 3; ++i) {
        int p = tid + i*256;
        uint uq = qrow[p], uk = krow[p];
        qv[i].x = bf2f(uq & 0xffffu); qv[i].y = bf2f(uq >> 16);
        kv[i].x = bf2f(uk & 0xffffu); kv[i].y = bf2f(uk >> 16);
        sq += qv[i].x*qv[i].x + qv[i].y*qv[i].y;
        sk += kv[i].x*kv[i].x + kv[i].y*kv[i].y;
    }
#pragma unroll
    for (int off = 1; off < 64; off <<= 1) {
        sq += __shfl_xor(sq, off);
        sk += __shfl_xor(sk, off);
    }
    __shared__ float red[4][2];
    if (lane == 0) { red[wave][0] = sq; red[wave][1] = sk; }
    __syncthreads();
    sq = red[0][0] + red[1][0] + red[2][0] + red[3][0];
    sk = red[0][1] + red[1][1] + red[2][1] + red[3][1];
    const float rmsq = rsqrtf(sq * (1.f/DIM) + 1e-6f);
    const float rmsk = rsqrtf(sk * (1.f/DIM) + 1e-6f);

    const int hh = gsz[1], ww = gsz[2];
    const int fidx = s / (hh*ww), rem = s % (hh*ww);
    const int hidx = rem / ww,  widx = rem % ww;
    // fold 1/sqrt(128) * log2(e): softmax runs in exp2 domain
    const float qscale = rmsq * (0.08838834764831845f * 1.4426950408889634f);

#pragma unroll
    for (int i = 0; i < 3; ++i) {
        int p = tid + i*256;               // pair index 0..767
        int c = p & 63, head = p >> 6;
        int coord = (c < 22) ? fidx : (c < 43) ? hidx : widx;
        float cv = fcos[coord*64 + c], sv = fsin[coord*64 + c];
        float2 gqv = reinterpret_cast<const float2*>(gq)[p];
        float2 gkv = reinterpret_cast<const float2*>(gk)[p];
        float a = qv[i].x * qscale * gqv.x, b = qv[i].y * qscale * gqv.y;
        uint qo = cvtpk(a*cv - b*sv, a*sv + b*cv);
        a = kv[i].x * rmsk * gkv.x; b = kv[i].y * rmsk * gkv.y;
        uint ko = cvtpk(a*cv - b*sv, a*sv + b*cv);
        size_t off = (((size_t)head * S_LEN + s) * HD + 2*c) >> 1;  // uint idx
        reinterpret_cast<uint*>(q_r)[off] = qo;
        reinterpret_cast<uint*>(k_r)[off] = ko;
    }
}

// ---------------------------------------------------------------------------
// 5) Flash attention, 32x32x16 MFMA with KEY-SPLIT wave pairs (R14-verified):
//    waves {2p,2p+1} share q-rows; wave khalf=w&1 handles keys
//    [kt*64+khalf*32, +32). LDS reads/wave-iter 16 b128, P in-register
//    (cvt_pk + permlane32_swap). End merge via freed Kl/Vl space.
//    K+V staged dbuf w/ XOR chunk swizzle.
//    NOTE: V-direct-to-reg attempted twice (R10/R12) — compiler-defeated.
//    NOTE: setprio on this structure measured within noise (R19) — omitted.
// ---------------------------------------------------------------------------
__global__ __launch_bounds__(256) void attn_fwd(
    const ushort* __restrict__ q_r, const ushort* __restrict__ k_r,
    const ushort* __restrict__ v_t, const int* __restrict__ seq_lens,
    ushort* __restrict__ attn_out)
{
    __shared__ ushort Kl[2][64 * 128];   // 2 x 16 KB (reused as merge Obuf)
    __shared__ ushort Vl[2][128 * 64];   // 2 x 16 KB (reused as merge MLbuf)
    const int tid  = threadIdx.x;
    const int wave = tid >> 6, lane = tid & 63;
    const int n  = blockIdx.y;
    const int seq = seq_lens[0];
    const int khalf = wave & 1, pair = wave >> 1;
    const int ql = lane & 31, h = lane >> 5, sw = lane & 7;
    const int qrow = blockIdx.x * 64 + pair * 32 + ql;
    const ushort* Qh = q_r + (size_t)n * S_LEN * HD;
    const ushort* Kh = k_r + (size_t)n * S_LEN * HD;
    const ushort* Vh = v_t + (size_t)n * HD * S_LEN;

    const int kj_row[4] = { (0*256+tid)>>4, (1*256+tid)>>4, (2*256+tid)>>4, (3*256+tid)>>4 };
    const int kj_w  = tid & 15;
    const int vj_d[4]  = { (0*256+tid)>>3, (1*256+tid)>>3, (2*256+tid)>>3, (3*256+tid)>>3 };
    const int vj_w  = tid & 7;

    bf16x8 qf[8];   // Q[qrow][c*16 + h*8 ..+7] (B-frag: col=q=ql, k=h*8+e)
#pragma unroll
    for (int c = 0; c < 8; ++c)
        qf[c] = *reinterpret_cast<const bf16x8*>(Qh + (size_t)qrow * HD + c*16 + h*8);

    f32x16 oacc[4] = {};   // oacc[db][j] = O[d=db*32+(j&3)+8*(j>>2)+4h][q=ql]
    float mrun = -1e30f, lrun = 0.f;

    const int nt = (seq + 63) >> 6;

#define STAGE(buf, kbase)                                                     \
    do {                                                                      \
        _Pragma("unroll")                                                     \
        for (int t = 0; t < 4; ++t) {                                         \
            int row = kj_row[t];                                              \
            GLOAD16(Kh + (size_t)((kbase) + row) * HD + ((kj_w ^ (row & 7)) * 8), \
                    &Kl[buf][(t*256 + wave*64) * 8]);                         \
        }                                                                     \
        _Pragma("unroll")                                                     \
        for (int t = 0; t < 4; ++t) {                                         \
            int d = vj_d[t];                                                  \
            GLOAD16(Vh + (size_t)d * S_LEN + (kbase) + ((vj_w ^ (d & 7)) * 8), \
                    &Vl[buf][(t*256 + wave*64) * 8]);                         \
        }                                                                     \
    } while (0)

    STAGE(0, 0);
    asm volatile("s_waitcnt vmcnt(0)" ::: "memory");
    __syncthreads();

    int cur = 0;
    for (int kt = 0; kt < nt; ++kt) {
        const int k0 = kt * 64 + khalf * 32;   // this wave's 32-key block
        if (kt + 1 < nt) STAGE(cur ^ 1, (kt+1) * 64);

        // ---- QK^T swapped (32x32x16): sf[j] = S[key=k0+(j&3)+8*(j>>2)+4h][q=ql]
        f32x16 sf = {};
        const ushort* kl = &Kl[cur][(khalf*32 + ql) * 128];
#pragma unroll
        for (int c = 0; c < 8; ++c)
            sf = __builtin_amdgcn_mfma_f32_32x32x16_bf16(
                *reinterpret_cast<const bf16x8*>(kl + ((2*c + h) ^ sw) * 8),
                qf[c], sf, 0, 0, 0);
        if (k0 + 32 > seq) {   // safety mask (S divisible by 64)
#pragma unroll
            for (int j = 0; j < 16; ++j)
                if (k0 + (j&3) + 8*(j>>2) + 4*h >= seq) sf[j] = -1e30f;
        }
        // ---- row max: 15-op in-lane tree + 1 shfl (combine h-halves)
        float pm = sf[0];
#pragma unroll
        for (int j = 1; j < 16; ++j) pm = fmaxf(pm, sf[j]);
        pm = fmaxf(pm, __shfl_xor(pm, 32));
        // ---- defer-max (THR=8, log2 domain)
        if (!__all(pm - mrun <= 8.f)) {
            float mn = fmaxf(mrun, pm);
            float scl = fexp2(mrun - mn);
            mrun = mn;
            lrun *= scl;
#pragma unroll
            for (int db = 0; db < 4; ++db)
#pragma unroll
                for (int j = 0; j < 16; ++j) oacc[db][j] *= scl;
        }
        // ---- P = exp2(S - mrun), in-lane sum + 1 shfl
        float ps = 0.f;
#pragma unroll
        for (int j = 0; j < 16; ++j) {
            float e = fexp2(sf[j] - mrun);
            sf[j] = e;
            ps += e;
        }
        ps += __shfl_xor(ps, 32);
        lrun += ps;
        // ---- P -> bf16 B-frags in-register (cvt_pk + permlane32_swap, R7)
        uint u0 = cvtpk(sf[0],  sf[1]),  u1 = cvtpk(sf[2],  sf[3]);
        uint u2 = cvtpk(sf[4],  sf[5]),  u3 = cvtpk(sf[6],  sf[7]);
        uint u4 = cvtpk(sf[8],  sf[9]),  u5 = cvtpk(sf[10], sf[11]);
        uint u6 = cvtpk(sf[12], sf[13]), u7 = cvtpk(sf[14], sf[15]);
        asm("v_permlane32_swap_b32 %0, %1" : "+v"(u0), "+v"(u2));
        asm("v_permlane32_swap_b32 %0, %1" : "+v"(u1), "+v"(u3));
        asm("v_permlane32_swap_b32 %0, %1" : "+v"(u4), "+v"(u6));
        asm("v_permlane32_swap_b32 %0, %1" : "+v"(u5), "+v"(u7));
        union { uint uu[4]; bf16x8 v; } fa, fb;
        fa.uu[0] = u0; fa.uu[1] = u1; fa.uu[2] = u2; fa.uu[3] = u3; // keys 0..15
        fb.uu[0] = u4; fb.uu[1] = u5; fb.uu[2] = u6; fb.uu[3] = u7; // keys 16..31
        // ---- PV swapped: oacc[db] += mfma(V_frag, P_frag) -> O[d][q]
#pragma unroll
        for (int db = 0; db < 4; ++db) {
            const ushort* vl = &Vl[cur][(db*32 + ql) * 64];
            oacc[db] = __builtin_amdgcn_mfma_f32_32x32x16_bf16(
                *reinterpret_cast<const bf16x8*>(vl + ((khalf*4 + 0 + h) ^ sw) * 8),
                fa.v, oacc[db], 0, 0, 0);
            oacc[db] = __builtin_amdgcn_mfma_f32_32x32x16_bf16(
                *reinterpret_cast<const bf16x8*>(vl + ((khalf*4 + 2 + h) ^ sw) * 8),
                fb.v, oacc[db], 0, 0, 0);
        }

        if (kt + 1 < nt) {
            asm volatile("s_waitcnt vmcnt(0)" ::: "memory");
            __syncthreads();
            cur ^= 1;
        }
    }
#undef STAGE

    // ---- merge the two key-halves of each wave pair via freed LDS
    __syncthreads();
    float* Obuf  = (float*)&Kl[0][0];   // [2 pairs][128 d][32 q] = 8192 f32
    float* MLbuf = (float*)&Vl[0][0];   // [2 pairs][{m,l}][32 q]
    if (khalf == 1) {
#pragma unroll
        for (int db = 0; db < 4; ++db)
#pragma unroll
            for (int j = 0; j < 16; ++j) {
                int d = db*32 + (j&3) + 8*(j>>2) + 4*h;
                Obuf[pair*4096 + d*32 + ql] = oacc[db][j];
            }
        if (h == 0) { MLbuf[pair*64 + ql] = mrun; MLbuf[pair*64 + 32 + ql] = lrun; }
    }
    __syncthreads();
    if (khalf == 0) {
        float m2 = MLbuf[pair*64 + ql], l2 = MLbuf[pair*64 + 32 + ql];
        float mm = fmaxf(mrun, m2);
        float s1 = fexp2(mrun - mm), s2 = fexp2(m2 - mm);
        float ltot = lrun * s1 + l2 * s2;
        float inv = (ltot > 0.f) ? 1.f / ltot : 0.f;
#pragma unroll
        for (int db = 0; db < 4; ++db)
#pragma unroll
            for (int j = 0; j < 16; ++j) {
                int d = db*32 + (j&3) + 8*(j>>2) + 4*h;
                oacc[db][j] = (oacc[db][j] * s1 +
                               Obuf[pair*4096 + d*32 + ql] * s2) * inv;
            }
        // store 16x b64: d = db*32 + 8*jg + 4h + (0..3), row qrow
#pragma unroll
        for (int db = 0; db < 4; ++db)
#pragma unroll
            for (int jg = 0; jg < 4; ++jg) {
                uint2 pkt;
                pkt.x = cvtpk(oacc[db][jg*4+0], oacc[db][jg*4+1]);
                pkt.y = cvtpk(oacc[db][jg*4+2], oacc[db][jg*4+3]);
                *reinterpret_cast<uint2*>(
                    &attn_out[(size_t)qrow * DIM + n*HD + db*32 + jg*8 + 4*h]) = pkt;
            }
    }
}

// ---------------------------------------------------------------------------
extern "C" void kernel_launch(void* const* d_in, const int* in_sizes, int n_in,
                              void* d_out, int out_size, void* d_ws, size_t ws_size,
                              hipStream_t stream)
{
    const float* x    = (const float*)d_in[0];
    const int*   seqL = (const int*)  d_in[1];
    const int*   gsz  = (const int*)  d_in[2];
    const float* fcos = (const float*)d_in[3];
    const float* fsin = (const float*)d_in[4];
    const float* Wq   = (const float*)d_in[5];
    const float* bq   = (const float*)d_in[6];
    const float* Wk   = (const float*)d_in[7];
    const float* bk   = (const float*)d_in[8];
    const float* Wv   = (const float*)d_in[9];
    const float* bv   = (const float*)d_in[10];
    const float* Wo   = (const float*)d_in[11];
    const float* bo   = (const float*)d_in[12];
    const float* gq   = (const float*)d_in[13];
    const float* gk   = (const float*)d_in[14];
    float* out = (float*)d_out;

    char* ws = (char*)d_ws;
    ushort* xb  = (ushort*)ws;                     // S*DIM         =  8.26 MB
    ushort* wb  = xb  + (size_t)S_LEN * DIM;       // 4*DIM*DIM     = 18.87 MB
    ushort* qkb = wb  + 4*(size_t)DIM*DIM;         // S*3072        = 16.52 MB
    ushort* v_t = qkb + (size_t)S_LEN * 2*DIM;     // DIM*S         =  8.26 MB
    ushort* q_r = v_t + (size_t)DIM * S_LEN;       // S*DIM         =  8.26 MB
    ushort* k_r = q_r + (size_t)S_LEN * DIM;       // S*DIM         =  8.26 MB
    ushort* ao  = k_r + (size_t)S_LEN * DIM;       // S*DIM         =  8.26 MB
    // total ws use: ~76.7 MB

    convert_all<<<13248, 256, 0, stream>>>(x, Wq, Wk, Wv, Wo, xb, wb);
    gemm_qkv<<<dim3(21, 36), 256, 0, stream>>>(xb, wb, bq, bk, bv,
                                               qkb, v_t, DIM);
    normrope<<<S_LEN, 256, 0, stream>>>(qkb, gsz, gq, gk, fcos, fsin, q_r, k_r);
    attn_fwd<<<dim3(42, 12), 256, 0, stream>>>(q_r, k_r, v_t, seqL, ao);
    gemm_bt2<<<dim3(21, 24), 256, 0, stream>>>(ao, wb + 3*(size_t)DIM*DIM,
                                               bo, out, S_LEN, DIM, DIM);
}